// Round 4
// baseline (115357.593 us; speedup 1.0000x reference)
//
#include <hip/hip_runtime.h>

#define NHID 512
#define NXW  128
#define TLEN 16384
#define STEPS (TLEN - NXW)      // 16256
#define G    32                 // persistent workgroups
#define B    512                // 8 waves per WG
#define RSLOTS 8                // sync ring depth (32 KB -> stays IC/L2-hot)
#define XWIN 640                // 512-slot circular x window + 128 mirror
#define SLICE 68                // padded h-slice pitch (floats): 64 + 4 pad

#define FOR4(M)  M(0) M(1) M(2) M(3)
#define FOR16(M) M(0) M(1) M(2) M(3) M(4) M(5) M(6) M(7) \
                 M(8) M(9) M(10) M(11) M(12) M(13) M(14) M(15)
#define FOR8(M)  M(0) M(1) M(2) M(3) M(4) M(5) M(6) M(7)

__device__ __forceinline__ float sigmoid_f(float v) { return 1.f / (1.f + __expf(-v)); }
__device__ __forceinline__ float tanh_f(float v)    { return 1.f - 2.f / (1.f + __expf(2.f * v)); }

#define AL(p) __hip_atomic_load((p), __ATOMIC_RELAXED, __HIP_MEMORY_SCOPE_AGENT)

// ---------------------------------------------------------------------------
// R4: barrier-free, wave-autonomous step.
//
// Each wave owns 2 complete rows (WG g, wave w -> rows g*16+2w, g*16+2w+1).
// Lane l: output group gi=l>>3 (2 rows x 4 gates), k-slice ks=l&7 (64 h's).
// Per step, a wave: polls the FULL 512-word ring slot cooperatively (lane l
// tag-checks words 8l..8l+7 = exactly one 64B line), stages h into its own
// padded LDS slice, computes all 4 gate dots for its 2 rows (8-lane shuffle
// reduce), activates, gathers gates in-wave, updates c, publishes 2 ring
// words. NO __syncthreads on the step path, no wave0 serialization - the
// R0..R3 back-end (barrier + partials LDS round-trip + wave0-only tail,
// ~400-600 cy with 7/8 waves idle) is gone.
//
// Ring word = {tag:32 | h_bits:32}; consumer of step t polls slot (t-1)&7
// until tag == t-1. Harness 0xAA poison = tag 0xAAAAAAAA, never a valid t.
// Slot reuse race-free (unchanged argument): any wave at step t has
// validated all 512 tags t-1, so every producer passed step t-1, so every
// reader of tag <= t-2 is done; overwriting slot t&7 (tag t-8) is safe.
// Ring coupling also bounds wave skew to <=2 steps, which keeps the
// barrier-free x_win refill safe (129-step dead-slot margin, R2-verified
// scheme).
//
// LDS h_stage: per-wave private [8][SLICE=68] floats. Read side: lane reads
// float4s at ks*68 floats pitch -> the 8 distinct ks land on disjoint bank
// quads (68 mod 32 = 4), same-ks lanes broadcast => conflict-free.
// ---------------------------------------------------------------------------
__launch_bounds__(B, 2)
__global__ void lstm_persistent(
    const float* x,
    const float* Wf, const float* Uf, const float* bf,
    const float* Wi, const float* Ui, const float* bi,
    const float* Wo, const float* Uo, const float* bo,
    const float* Wc, const float* Uc, const float* bc,
    unsigned long long* ring,     // [RSLOTS][NHID] packed {tag,h}
    float* h_hist)                // [STEPS][NHID] for mu only
{
    __shared__ float x_win[XWIN];
    __shared__ __align__(16) float h_stage[8][8 * SLICE];   // per-wave private

    const int tid = threadIdx.x;
    const int g   = blockIdx.x;
    const int w   = tid >> 6;            // wave 0..7
    const int l   = tid & 63;
    const int ks  = l & 7;               // k-slice (64 h values)
    const int gi  = l >> 3;              // output group 0..7 (2 rows x 4 gates)
    const int gate = gi & 3;             // 0=f 1=i 2=o 3=c
    const int rhat = l >> 5;             // row sub 0/1 (== gi>>2)
    const int row  = g * 16 + 2 * w + rhat;

    const float* Utab[4] = {Uf, Ui, Uo, Uc};
    const float* Wtab[4] = {Wf, Wi, Wo, Wc};
    const float* Btab[4] = {bf, bi, bo, bc};

    // pinned weights: U[row(gate)][ks*64 .. +64) = 16 float4; W slice = 4 float4
    const float4* Up = (const float4*)(Utab[gate] + (size_t)row * NHID + ks * 64);
    #define DECLU(i) float4 u##i = Up[i];
    FOR16(DECLU)
    const float4* Wp = (const float4*)(Wtab[gate] + row * NXW + ks * 16);
    #define DECLW(i) float4 wv##i = Wp[i];
    FOR4(DECLW)
    #define PIN(r) asm volatile("" : "+v"(r.x), "+v"(r.y), "+v"(r.z), "+v"(r.w));
    #define PINU(i) PIN(u##i)
    FOR16(PINU)
    #define PINW(i) PIN(wv##i)
    FOR4(PINW)

    const float bias = Btab[gate][row];
    float c_prev = 0.f;                  // per-lane copy of own row's c

    // zero own h_stage (h[-1] = 0): lane l owns dwords for h[8l..8l+8)
    {
        float* dst = &h_stage[w][gi * SLICE + ((l << 3) & 63)];
        #pragma unroll
        for (int j = 0; j < 8; ++j) dst[j] = 0.f;
    }
    // x_win prologue: fill x[0..511] + mirror of first 128
    {
        float v = x[tid];
        x_win[tid] = v;
        if (tid < XWIN - 512) x_win[512 + tid] = v;
    }
    __syncthreads();                     // ONLY barrier (prologue)

    for (int t = 0; t < STEPS; ++t) {
        // background x refill by wave 7: x[t+256 .. t+384) into dead slots.
        // Safe: readers at t' (skew <=2) touch at most x[t'+127]; margin 129.
        if (((t & 127) == 0) && w == 7) {
            int j = t + 256 + (l << 1);
            #pragma unroll
            for (int k2 = 0; k2 < 2; ++k2) {
                int jj = j + k2;
                float v = (jj < TLEN) ? x[jj] : 0.f;
                int s = jj & 511;
                x_win[s] = v;
                if (s < XWIN - 512) x_win[512 + s] = v;
            }
        }

        const unsigned want = (unsigned)(t - 1);
        const unsigned long long* base =
            ring + ((size_t)((t - 1) & (RSLOTS - 1)) << 9) + (l << 3);

        // issue all 8 poll loads up front (one 64B line per lane)
        unsigned long long p0, p1, p2, p3, p4, p5, p6, p7;
        if (t > 0) {
            p0 = AL(base + 0); p1 = AL(base + 1);
            p2 = AL(base + 2); p3 = AL(base + 3);
            p4 = AL(base + 4); p5 = AL(base + 5);
            p6 = AL(base + 6); p7 = AL(base + 7);
        }

        // x-projection for this lane's output, slice ks*16 of the 128-window
        float xa0 = 0.f, xa1 = 0.f;
        {
            const int xb = (t & 511) + ks * 16;
            #define XF(i, A) A += wv##i.x * x_win[xb + 4*i]     \
                                + wv##i.y * x_win[xb + 4*i + 1] \
                                + wv##i.z * x_win[xb + 4*i + 2] \
                                + wv##i.w * x_win[xb + 4*i + 3];
            XF(0, xa0) XF(1, xa1) XF(2, xa0) XF(3, xa1)
        }
        const float xacc = xa0 + xa1;

        // validate the 8 tags (per-lane spin; words land L2-hot)
        if (t > 0) {
            int guard = 1 << 22;
            #define SPIN(j) while ((unsigned)(p##j >> 32) != want) {            \
                                p##j = AL(base + j);                            \
                                if (--guard == 0) break; }
            FOR8(SPIN)
            // stage h[8l..8l+8) into own wave's padded slice
            float* dst = &h_stage[w][gi * SLICE + ((l << 3) & 63)];
            dst[0] = __uint_as_float((unsigned)p0);
            dst[1] = __uint_as_float((unsigned)p1);
            dst[2] = __uint_as_float((unsigned)p2);
            dst[3] = __uint_as_float((unsigned)p3);
            dst[4] = __uint_as_float((unsigned)p4);
            dst[5] = __uint_as_float((unsigned)p5);
            dst[6] = __uint_as_float((unsigned)p6);
            dst[7] = __uint_as_float((unsigned)p7);
        }
        // NOTE: no barrier - each wave reads only its own h_stage slice;
        // lgkmcnt ordering (compiler-inserted) covers write->read in-wave.

        // U @ h for this lane's output over k-slice ks: 64 FMA, 4 accumulators
        float ac0 = xacc, ac1 = 0.f, ac2 = 0.f, ac3 = 0.f;
        const float4* hb4 = (const float4*)&h_stage[w][ks * SLICE];
        #define UF(i, A) { float4 hv = hb4[i];                    \
                           A += u##i.x * hv.x + u##i.y * hv.y     \
                              + u##i.z * hv.z + u##i.w * hv.w; }
        UF(0,  ac0) UF(1,  ac1) UF(2,  ac2) UF(3,  ac3)
        UF(4,  ac0) UF(5,  ac1) UF(6,  ac2) UF(7,  ac3)
        UF(8,  ac0) UF(9,  ac1) UF(10, ac2) UF(11, ac3)
        UF(12, ac0) UF(13, ac1) UF(14, ac2) UF(15, ac3)
        float acc = (ac0 + ac1) + (ac2 + ac3);

        // 8-lane (k-slice) reduce within the output group: 3 shuffle hops
        acc += __shfl_xor(acc, 1, 64);
        acc += __shfl_xor(acc, 2, 64);
        acc += __shfl_xor(acc, 4, 64);
        const float pre = acc + bias;

        // activate own gate; gather the row's 4 gates in-wave
        const float a = (gate < 3) ? sigmoid_f(pre) : tanh_f(pre);
        const int bl = l & 39;                        // (l&7)|(l&32)
        const float af = __shfl(a, bl,      64);
        const float ai = __shfl(a, bl + 8,  64);
        const float ao = __shfl(a, bl + 16, 64);
        const float ag = __shfl(a, bl + 24, 64);
        const float c  = af * c_prev + ai * ag;
        c_prev = c;
        const float h = ao * tanh_f(c);

        // publish: one lane per row (lanes 0 and 32)
        if ((l & 31) == 0) {
            unsigned long long pv =
                ((unsigned long long)(unsigned)t << 32)
                | (unsigned long long)__float_as_uint(h);
            __hip_atomic_store(
                ring + ((size_t)(t & (RSLOTS - 1)) << 9) + row, pv,
                __ATOMIC_RELAXED, __HIP_MEMORY_SCOPE_AGENT);
            h_hist[(size_t)t * NHID + row] = h;       // mu only, off-path
        }
    }
}

// ---------------------------------------------------------------------------
// epilogue: mu[t] = Ahy . h_hist[t] + by   (one wave per t)
// ---------------------------------------------------------------------------
__global__ void mu_kernel(const float* __restrict__ h_hist,
                          const float* __restrict__ Ahy,
                          const float* __restrict__ by,
                          float* __restrict__ outp, int steps)
{
    int wave = threadIdx.x >> 6;
    int lane = threadIdx.x & 63;
    int t = blockIdx.x * 4 + wave;
    if (t >= steps) return;
    const float* h = h_hist + (size_t)t * NHID;
    float p = 0.f;
    #pragma unroll
    for (int e = 0; e < 8; e++)
        p += Ahy[e * 64 + lane] * h[e * 64 + lane];
    #pragma unroll
    for (int off = 32; off; off >>= 1) p += __shfl_down(p, off, 64);
    if (lane == 0) outp[t] = p + by[0];
}

// ---------------------------------------------------------------------------
extern "C" void kernel_launch(void* const* d_in, const int* in_sizes, int n_in,
                              void* d_out, int out_size, void* d_ws, size_t ws_size,
                              hipStream_t stream)
{
    const float* x  = (const float*)d_in[0];
    const float* Wf = (const float*)d_in[1];
    const float* Uf = (const float*)d_in[2];
    const float* bf = (const float*)d_in[3];
    const float* Wi = (const float*)d_in[4];
    const float* Ui = (const float*)d_in[5];
    const float* bi = (const float*)d_in[6];
    const float* Wo = (const float*)d_in[7];
    const float* Uo = (const float*)d_in[8];
    const float* bo = (const float*)d_in[9];
    const float* Wc = (const float*)d_in[10];
    const float* Uc = (const float*)d_in[11];
    const float* bc = (const float*)d_in[12];
    const float* Ahy = (const float*)d_in[13];
    const float* by  = (const float*)d_in[14];

    unsigned long long* ring = (unsigned long long*)d_ws;        // 32 KB
    float* h_hist = (float*)((char*)d_ws + RSLOTS * NHID * 8);   // ~33.3 MB

    lstm_persistent<<<G, B, 0, stream>>>(x, Wf, Uf, bf, Wi, Ui, bi,
                                         Wo, Uo, bo, Wc, Uc, bc, ring, h_hist);
    int muBlocks = (STEPS + 3) / 4;
    mu_kernel<<<muBlocks, 256, 0, stream>>>(h_hist, Ahy, by, (float*)d_out, STEPS);
}

// Round 6
// 25902.988 us; speedup vs baseline: 4.4534x; 4.4534x over previous
//
#include <hip/hip_runtime.h>

#define NHID 512
#define NXW  128
#define TLEN 16384
#define STEPS (TLEN - NXW)      // 16256
#define GRID 256                // all launched; 32 elected participants persist
#define B    512                // 8 waves per WG
#define RPW  16                 // hidden rows owned per WG
#define RSLOTS 4                // sync ring depth (16 KB; R1-passed config)

#define XMAGIC 0x51E00000u      // xcc publish magic (rejects 0xAA poison & zeros)
#define AMAGIC 0x600D0000u      // assignment magic
#define GOFLAG 0x60606060u      // election-done flag

#define FOR4(M)  M(0) M(1) M(2) M(3)
#define FOR16(M) M(0) M(1) M(2) M(3) M(4) M(5) M(6) M(7) \
                 M(8) M(9) M(10) M(11) M(12) M(13) M(14) M(15)

__device__ __forceinline__ float sigmoid_f(float v) { return 1.f / (1.f + __expf(-v)); }
__device__ __forceinline__ float tanh_f(float v)    { return 1.f - 2.f / (1.f + __expf(2.f * v)); }

#define ALD(p, ORD) __hip_atomic_load((p), ORD, __HIP_MEMORY_SCOPE_AGENT)
#define AST(p, v, ORD) __hip_atomic_store((p), (v), ORD, __HIP_MEMORY_SCOPE_AGENT)

// sc0 = L1-bypass; rendezvous at the XCD-shared L2. Compile-proven (R1 ran).
__device__ __forceinline__ unsigned long long ld_ring_l2(const unsigned long long* p) {
    unsigned long long v;
    asm volatile("global_load_dwordx2 %0, %1, off sc0\n\ts_waitcnt vmcnt(0)"
                 : "=v"(v) : "v"(p) : "memory");
    return v;
}
__device__ __forceinline__ void st_ring_l2(unsigned long long* p, unsigned long long v) {
    asm volatile("global_store_dwordx2 %0, %1, off sc0" :: "v"(p), "v"(v) : "memory");
}

// ---------------------------------------------------------------------------
// R6 = R0 skeleton (verified 25.6 ms) + ADVISORY single-XCD election
//      + dual-path ring (sc0 fast / agent fallback, sticky degrade).
//
// Election (one-time): every WG publishes {XMAGIC|xcc} from
// hwreg(HW_REG_XCC_ID). WG0 collects (guarded; on guard expiry falls back to
// assigning bids 0..31 = R0 membership), picks the XCD holding >=32 WGs
// (pigeonhole: 256 WGs / 8 XCDs), assigns slots 0..31 to 32 WGs of that XCD,
// publishes assignments then GOFLAG (release). Participants find their slot;
// non-participants rescan briefly (covers stale-GO mid-update races under
// graph replay without workspace re-poison) then exit.
//
// Ring word = {tag:32 | h_bits:32}; consumer of step t polls slot (t-1)&3
// until tag == t-1. 0xAA poison = tag 0xAAAAAAAA, never a valid t. Slot
// reuse race-free: a producer publishing tag t validated all 512 tags t-1,
// so every WG reached step t-1's tail, so nobody still reads tags <= t-2;
// overwriting slot t&3 (tag t-4) is safe (depth >= 2 suffices; 4 = margin).
//
// Dual path: producers store sc0 (XCD-local L2) THEN agent-scope shadow
// (IC). Consumers poll sc0; after 64 misses a lane STICKILY degrades to
// agent-atomic polling (R0's verified fabric). Same-XCD placement makes the
// fast path hold for everyone; ANY placement/semantics failure degrades the
// kernel to R0 behavior within a few steps instead of hanging (R5's bug).
// ---------------------------------------------------------------------------
__launch_bounds__(B, 2)
__global__ void lstm_persistent(
    const float* x,
    const float* Wf, const float* Uf, const float* bf,
    const float* Wi, const float* Ui, const float* bi,
    const float* Wo, const float* Uo, const float* bo,
    const float* Wc, const float* Uc, const float* bc,
    unsigned long long* ring,     // [RSLOTS][NHID] packed {tag,h}
    unsigned* elect,              // [256] xcc | [32] assign | [1] go
    float* h_hist)                // [STEPS][NHID] for mu only
{
    __shared__ float x_win[256];                    // x ring: refill every 128 steps
    __shared__ __align__(16) float h_buf[8][64];    // per-wave h-slice staging
    __shared__ float partials[2][B];                // double-buffered
    __shared__ int sh_slot;

    const int tid = threadIdx.x;
    const int bid = blockIdx.x;

    unsigned* xcc_reg = elect;          // [256]
    unsigned* assign  = elect + 256;    // [32]
    unsigned* gflag   = elect + 288;    // [1]

    // ---- publish own XCC (before any wait: no circular dependency) ----
    if (tid == 0) {
        unsigned xcc;
        asm volatile("s_getreg_b32 %0, hwreg(HW_REG_XCC_ID)" : "=s"(xcc));
        AST(&xcc_reg[bid], XMAGIC | (xcc & 7u), __ATOMIC_RELAXED);
    }

    // ---- WG0: collect (guarded), pick XCD, assign, release ----
    if (bid == 0) {
        unsigned* lds = (unsigned*)&partials[0][0];     // scratch reuse
        if (tid < 256) {
            unsigned v; int guard = 1 << 20;
            for (;;) {
                v = ALD(&xcc_reg[tid], __ATOMIC_RELAXED);
                if ((v & 0xFFFFFF00u) == XMAGIC) break;
                if (--guard == 0) { v = XMAGIC | 8u; break; }   // unknown bucket
            }
            lds[tid] = v & 15u;
        }
        __syncthreads();
        if (tid == 0) {
            int cnt[9] = {0,0,0,0,0,0,0,0,0};
            for (int i = 0; i < 256; ++i) { unsigned c = lds[i]; cnt[c <= 8u ? c : 8u]++; }
            int best = 0;
            for (int i = 1; i < 8; ++i) if (cnt[i] > cnt[best]) best = i;
            int s = 0;
            if (cnt[best] >= 32) {
                for (int i = 0; i < 256 && s < 32; ++i)
                    if ((int)lds[i] == best)
                        AST(&assign[s++], AMAGIC | (unsigned)i, __ATOMIC_RELAXED);
            } else {                                     // fallback: R0 membership
                for (; s < 32; ++s)
                    AST(&assign[s], AMAGIC | (unsigned)s, __ATOMIC_RELAXED);
            }
            AST(gflag, GOFLAG, __ATOMIC_RELEASE);
        }
        __syncthreads();
    }

    // ---- find own slot (guarded wait + brief rescan for stale-GO races) ----
    if (tid == 0) {
        unsigned gv; int guard = 1 << 22;
        do { gv = ALD(gflag, __ATOMIC_ACQUIRE); }
        while (gv != GOFLAG && --guard);
        int slot = -1;
        if (gv == GOFLAG) {
            const unsigned me = AMAGIC | (unsigned)bid;
            for (int r = 0; r < 64 && slot < 0; ++r)
                for (int s = 0; s < 32; ++s)
                    if (ALD(&assign[s], __ATOMIC_RELAXED) == me) { slot = s; break; }
        }
        sh_slot = slot;
    }
    __syncthreads();
    const int g = sh_slot;
    if (g < 0) return;                  // not elected: free the CU slot

    // ---- R0-verified compute skeleton ----
    const int w   = tid >> 6;            // wave = k-slice 0..7
    const int l   = tid & 63;            // output 0..63
    const int q   = l >> 4;              // gate 0=f 1=i 2=o 3=c
    const int row = g * RPW + (l & 15);

    const float* Utab[4] = {Uf, Ui, Uo, Uc};
    const float* Wtab[4] = {Wf, Wi, Wo, Wc};
    const float* Btab[4] = {bf, bi, bo, bc};

    const float4* Up = (const float4*)(Utab[q] + (size_t)row * NHID + w * 64);
    #define DECLU(i) float4 u##i = Up[i];
    FOR16(DECLU)
    const float4* Wp = (const float4*)(Wtab[q] + row * NXW + w * 16);
    #define DECLW(i) float4 wv##i = Wp[i];
    FOR4(DECLW)
    #define PIN(r) asm volatile("" : "+v"(r.x), "+v"(r.y), "+v"(r.z), "+v"(r.w));
    #define PINU(i) PIN(u##i)
    FOR16(PINU)
    #define PINW(i) PIN(wv##i)
    FOR4(PINW)

    float bias = 0.f, c_prev = 0.f;
    if (w == 0) bias = Btab[q][row];

    h_buf[w][l] = 0.f;                   // h[-1] = 0 (own wave reads only)

    bool lfast = true;                   // sticky per-lane fast-path flag

    for (int t = 0; t < STEPS; ++t) {
        if ((t & 127) == 0) {            // x window refill (covers x[t..t+255])
            __syncthreads();
            if (tid < 256) {
                int gi = t + tid;
                x_win[tid] = (gi < TLEN) ? x[gi] : 0.f;
            }
            __syncthreads();
        }

        const unsigned want = (unsigned)(t - 1);
        const unsigned long long* src =
            ring + ((size_t)((t - 1) & (RSLOTS - 1)) << 9) + (w * 64 + l);

        // degraded path: issue agent probe early (overlaps x-projection)
        unsigned long long vv = 0;
        if (t > 0 && !lfast) vv = ALD(src, __ATOMIC_RELAXED);

        // x-projection partial (independent of h), 2 accumulators
        float xa0 = 0.f, xa1 = 0.f;
        {
            const int xb = (t & 127) + w * 16;
            #define XF(i, A) A += wv##i.x * x_win[xb + 4*i]     \
                                + wv##i.y * x_win[xb + 4*i + 1] \
                                + wv##i.z * x_win[xb + 4*i + 2] \
                                + wv##i.w * x_win[xb + 4*i + 3];
            XF(0, xa0) XF(1, xa1) XF(2, xa0) XF(3, xa1)
        }
        const float xacc = xa0 + xa1;

        // poll own 8B ring word of h[t-1]
        if (t > 0) {
            if (lfast) {
                vv = ld_ring_l2(src);
                int miss = 0;
                while ((unsigned)(vv >> 32) != want) {
                    if (++miss > 64) { lfast = false; break; }   // sticky degrade
                    vv = ld_ring_l2(src);
                }
            }
            if (!lfast) {
                int guard = 1 << 20;
                while ((unsigned)(vv >> 32) != want && --guard)
                    vv = ALD(src, __ATOMIC_RELAXED);
            }
            h_buf[w][l] = __uint_as_float((unsigned)vv);
        }

        // U @ h slice: 64 FMA, 4 independent accumulators (R3-verified)
        float ac0 = xacc, ac1 = 0.f, ac2 = 0.f, ac3 = 0.f;
        const float4* hb4 = (const float4*)h_buf[w];
        #define UF(i, A) { float4 hv = hb4[i];                    \
                           A += u##i.x * hv.x + u##i.y * hv.y     \
                              + u##i.z * hv.z + u##i.w * hv.w; }
        UF(0,  ac0) UF(1,  ac1) UF(2,  ac2) UF(3,  ac3)
        UF(4,  ac0) UF(5,  ac1) UF(6,  ac2) UF(7,  ac3)
        UF(8,  ac0) UF(9,  ac1) UF(10, ac2) UF(11, ac3)
        UF(12, ac0) UF(13, ac1) UF(14, ac2) UF(15, ac3)
        const float acc = (ac0 + ac1) + (ac2 + ac3);

        partials[t & 1][tid] = acc;
        __syncthreads();                 // the ONE per-step barrier

        // wave-0 tail: reduce 8 k-slices, activate, combine, publish to ring
        if (w == 0) {
            const float* p = partials[t & 1];
            float r0 = p[64  + l] + p[128 + l];
            float r1 = p[192 + l] + p[256 + l];
            float r2 = p[320 + l] + p[384 + l];
            float r3 = p[448 + l];
            float pre = ((acc + bias) + r0) + ((r1 + r2) + r3);
            float a = (l < 48) ? sigmoid_f(pre) : tanh_f(pre);   // f,i,o / g
            float ai = __shfl(a, l + 16, 64);
            float ao = __shfl(a, l + 32, 64);
            float ag = __shfl(a, l + 48, 64);
            if (l < 16) {
                float c = a * c_prev + ai * ag;
                c_prev = c;
                float h = ao * tanh_f(c);
                unsigned long long pv =
                    ((unsigned long long)(unsigned)t << 32)
                    | (unsigned long long)__float_as_uint(h);
                unsigned long long* dst =
                    ring + ((size_t)(t & (RSLOTS - 1)) << 9) + row;
                st_ring_l2(dst, pv);                  // XCD-local L2 (fast path)
                AST(dst, pv, __ATOMIC_RELAXED);       // IC shadow (degraded path)
                h_hist[(size_t)t * NHID + row] = h;   // mu only, off-path
            }
        }
    }
}

// ---------------------------------------------------------------------------
// epilogue: mu[t] = Ahy . h_hist[t] + by   (one wave per t)
// ---------------------------------------------------------------------------
__global__ void mu_kernel(const float* __restrict__ h_hist,
                          const float* __restrict__ Ahy,
                          const float* __restrict__ by,
                          float* __restrict__ outp, int steps)
{
    int wave = threadIdx.x >> 6;
    int lane = threadIdx.x & 63;
    int t = blockIdx.x * 4 + wave;
    if (t >= steps) return;
    const float* h = h_hist + (size_t)t * NHID;
    float p = 0.f;
    #pragma unroll
    for (int e = 0; e < 8; e++)
        p += Ahy[e * 64 + lane] * h[e * 64 + lane];
    #pragma unroll
    for (int off = 32; off; off >>= 1) p += __shfl_down(p, off, 64);
    if (lane == 0) outp[t] = p + by[0];
}

// ---------------------------------------------------------------------------
extern "C" void kernel_launch(void* const* d_in, const int* in_sizes, int n_in,
                              void* d_out, int out_size, void* d_ws, size_t ws_size,
                              hipStream_t stream)
{
    const float* x  = (const float*)d_in[0];
    const float* Wf = (const float*)d_in[1];
    const float* Uf = (const float*)d_in[2];
    const float* bf = (const float*)d_in[3];
    const float* Wi = (const float*)d_in[4];
    const float* Ui = (const float*)d_in[5];
    const float* bi = (const float*)d_in[6];
    const float* Wo = (const float*)d_in[7];
    const float* Uo = (const float*)d_in[8];
    const float* bo = (const float*)d_in[9];
    const float* Wc = (const float*)d_in[10];
    const float* Uc = (const float*)d_in[11];
    const float* bc = (const float*)d_in[12];
    const float* Ahy = (const float*)d_in[13];
    const float* by  = (const float*)d_in[14];

    unsigned long long* ring = (unsigned long long*)d_ws;        // 16 KB
    unsigned* elect = (unsigned*)((char*)d_ws + 16384);          // ~1.2 KB used
    float* h_hist = (float*)((char*)d_ws + 32768);               // ~33.3 MB

    lstm_persistent<<<GRID, B, 0, stream>>>(x, Wf, Uf, bf, Wi, Ui, bi,
                                            Wo, Uo, bo, Wc, Uc, bc,
                                            ring, elect, h_hist);
    int muBlocks = (STEPS + 3) / 4;
    mu_kernel<<<muBlocks, 256, 0, stream>>>(h_hist, Ahy, by, (float*)d_out, STEPS);
}